// Round 17
// baseline (903.603 us; speedup 1.0000x reference)
//
#include <hip/hip_runtime.h>
#include <hip/hip_bf16.h>
#include <stdint.h>

typedef short bf16x8 __attribute__((ext_vector_type(8)));
typedef float floatx4 __attribute__((ext_vector_type(4)));

#define N_ROWS 65536
#define V_DIM 2048
#define E_DIM 1024

__device__ __forceinline__ short f2bf(float x) {
  union { float f; uint32_t u; } c; c.f = x;
  uint32_t r = (c.u + 0x7FFFu + ((c.u >> 16) & 1u)) >> 16;
  return (short)(uint16_t)r;
}
__device__ __forceinline__ float bf16f(short b) {
  union { uint32_t u; float f; } c; c.u = ((uint32_t)(uint16_t)b) << 16;
  return c.f;
}
// f32 -> OCP e4m3fn (RNE); values here are < 2.2, clamps for safety.
__device__ __forceinline__ uint32_t f2e4m3(float x) {
  union { float f; uint32_t u; } c; c.f = x;
  const uint32_t s = (c.u >> 24) & 0x80u;
  float ax = fabsf(x);
  uint32_t code;
  if (ax < 0.015625f) {                       // below min normal 2^-6
    code = (uint32_t)__float2int_rn(ax * 512.0f);   // 0..8 (8 == 2^-6 normal)
  } else {
    c.f = ax;
    uint32_t r = c.u + 0x7FFFFu + ((c.u >> 20) & 1u);
    code = (r >> 20) - (120u << 3);
    if (code > 0x7Eu) code = 0x7Eu;
  }
  return s | code;
}

__device__ __forceinline__ float wave_sum(float v) {
#pragma unroll
  for (int o = 32; o > 0; o >>= 1) v += __shfl_xor(v, o);
  return v;
}
__device__ __forceinline__ float wave_max(float v) {
#pragma unroll
  for (int o = 32; o > 0; o >>= 1) v = fmaxf(v, __shfl_xor(v, o));
  return v;
}

__device__ __forceinline__ void gll16(const void* g, void* l) {
  __builtin_amdgcn_global_load_lds(
      (const __attribute__((address_space(1))) void*)g,
      (__attribute__((address_space(3))) void*)l, 16, 0, 0);
}

// ---------------- merged normalize: blocks [0,V_DIM) do emb rows; the rest do
// z rows (4 rows/block).  FAST=1 skips the bf16 copies only the fallback uses.
template <int FAST>
__global__ __launch_bounds__(256) void k_norm_all(
    const float* __restrict__ Z, const float* __restrict__ W,
    short* __restrict__ zn, unsigned char* __restrict__ zn8,
    short* __restrict__ embn, short* __restrict__ embnT,
    unsigned char* __restrict__ embn8) {
  const int t = threadIdx.x;
  const int w = t >> 6, l = t & 63;
  if (blockIdx.x < V_DIM) {
    const int v = blockIdx.x;
    const float4 val = *(const float4*)&W[(size_t)v * E_DIM + t * 4];
    float ss = val.x * val.x + val.y * val.y + val.z * val.z + val.w * val.w;
    ss = wave_sum(ss);
    __shared__ float red[4];
    if (l == 0) red[w] = ss;
    __syncthreads();
    ss = red[0] + red[1] + red[2] + red[3];
    const float inv = 1.0f / fmaxf(sqrtf(ss), 1e-12f);
    short4 o;
    o.x = f2bf(val.x * inv);
    o.y = f2bf(val.y * inv);
    o.z = f2bf(val.z * inv);
    o.w = f2bf(val.w * inv);
    if (!FAST) *(short4*)&embn[(size_t)v * E_DIM + t * 4] = o;
    embnT[(size_t)(t * 4 + 0) * V_DIM + v] = o.x;
    embnT[(size_t)(t * 4 + 1) * V_DIM + v] = o.y;
    embnT[(size_t)(t * 4 + 2) * V_DIM + v] = o.z;
    embnT[(size_t)(t * 4 + 3) * V_DIM + v] = o.w;
    const uint32_t p = f2e4m3(val.x * inv) | (f2e4m3(val.y * inv) << 8) |
                       (f2e4m3(val.z * inv) << 16) | (f2e4m3(val.w * inv) << 24);
    *(uint32_t*)&embn8[(size_t)v * E_DIM + t * 4] = p;
  } else {
    const int row = (blockIdx.x - V_DIM) * 4 + w;
    const float* zr = Z + (size_t)row * E_DIM;
    float4 v[4];
    float ss = 0.f;
#pragma unroll
    for (int i = 0; i < 4; ++i) {
      v[i] = *(const float4*)&zr[(i * 64 + l) * 4];
      ss += v[i].x * v[i].x + v[i].y * v[i].y + v[i].z * v[i].z + v[i].w * v[i].w;
    }
    ss = wave_sum(ss);
    const float SCALE = 2.0f * (expf(-2.995732273553991f) + 1.0f);  // kappa_q / T
    const float inv = SCALE / fmaxf(sqrtf(ss), 1e-12f);
    unsigned char* zo8 = zn8 + (size_t)row * E_DIM;
#pragma unroll
    for (int i = 0; i < 4; ++i) {
      if (!FAST) {
        short4 o;
        o.x = f2bf(v[i].x * inv);
        o.y = f2bf(v[i].y * inv);
        o.z = f2bf(v[i].z * inv);
        o.w = f2bf(v[i].w * inv);
        *(short4*)&zn[(size_t)row * E_DIM + (i * 64 + l) * 4] = o;
      }
      const uint32_t p = f2e4m3(v[i].x * inv) | (f2e4m3(v[i].y * inv) << 8) |
                         (f2e4m3(v[i].z * inv) << 16) | (f2e4m3(v[i].w * inv) << 24);
      *(uint32_t*)&zo8[(i * 64 + l) * 4] = p;
    }
  }
}

// =============== GEMM1 (fp8): 256x128 tile, BK=64, ring-3 (72 KiB LDS),
// 2 blocks/CU.  Epilogue: software-pipelined U loads (ua/ub double-buffer,
// acc=64 leaves VGPR room) -> gumbel-exp -> Pb bf16 + partials.
__global__ __launch_bounds__(512, 4) void k_gemm_f8(
    const unsigned char* __restrict__ A8, const unsigned char* __restrict__ B8,
    const float* __restrict__ U, short* __restrict__ Pb,
    float* __restrict__ partials, int cpx) {
  __shared__ __align__(16) char Sm[73728];  // A ring: 3 x 16KB at 0; B ring: 3 x 8KB at 49152
  const int tid = threadIdx.x;
  const int wv = tid >> 6, lane = tid & 63;
  const int lr = lane & 15, lh = lane >> 4;
  const int wr = wv >> 1, wc = wv & 1;      // 4x2 wave grid (64x64 per wave)
  const int d = blockIdx.x;
  const int L = (d & 7) * cpx + (d >> 3);
  const int by = L >> 4, bx = L & 15;       // 256 x 16 tiles, row-major
  const int m0 = by * 256, n0 = bx * 128;
  const int sg8 = (((tid & 3) ^ ((tid >> 2) & 3)) << 4);
  const unsigned char* gA = A8 + (size_t)(m0 + (tid >> 2)) * E_DIM + sg8;
  const unsigned char* gB = B8 + (size_t)(n0 + (tid >> 2)) * E_DIM + sg8;
  const int t3 = lr & 3;
  const int soff0 = ((((lh >> 1) + 0) ^ t3) << 4) + (lh & 1) * 8;
  const int soff1 = ((((lh >> 1) + 2) ^ t3) << 4) + (lh & 1) * 8;
  const int arow = (wr * 64 + lr) * 64;
  const int brow = (wc * 64 + lr) * 64;

  // prologue: stage tiles 0 (slot0) and 1 (slot1), 3 loads each
#pragma unroll
  for (int t = 0; t < 2; ++t) {
    char* sa = Sm + t * 16384;
    char* sb = Sm + 49152 + t * 8192;
    gll16(gA + t * 64, sa + wv * 1024);
    gll16(gA + (size_t)128 * E_DIM + t * 64, sa + 8192 + wv * 1024);
    gll16(gB + t * 64, sb + wv * 1024);
  }
  asm volatile("s_waitcnt vmcnt(3)" ::: "memory");
  __builtin_amdgcn_s_barrier();
  __builtin_amdgcn_sched_barrier(0);

  floatx4 acc[4][4] = {};

#define DO_TILE(KT, CB, SN, STAGE, VMN)                                             \
  {                                                                                 \
    const char* Ab_ = Sm + (CB) * 16384;                                            \
    const char* Bb_ = Sm + 49152 + (CB) * 8192;                                     \
    char* An_ = Sm + (SN) * 16384;                                                  \
    char* Bn_ = Sm + 49152 + (SN) * 8192;                                           \
    const size_t kc_ = (size_t)((KT) + 2) * 64;                                     \
    long bfr[4], af[4];                                                             \
    _Pragma("unroll")                                                               \
    for (int n = 0; n < 4; ++n) bfr[n] = *(const long*)(Bb_ + brow + n * 1024 + soff0); \
    _Pragma("unroll")                                                               \
    for (int i = 0; i < 4; ++i) af[i] = *(const long*)(Ab_ + arow + i * 1024 + soff0); \
    if (STAGE) {                                                                    \
      gll16(gA + kc_, An_ + wv * 1024);                                             \
      gll16(gA + (size_t)128 * E_DIM + kc_, An_ + 8192 + wv * 1024);                \
    }                                                                               \
    __builtin_amdgcn_s_barrier();                                                   \
    asm volatile("s_waitcnt lgkmcnt(0)" ::: "memory");                              \
    __builtin_amdgcn_sched_barrier(0);                                              \
    __builtin_amdgcn_s_setprio(1);                                                  \
    _Pragma("unroll")                                                               \
    for (int i = 0; i < 4; ++i) {                                                   \
      _Pragma("unroll")                                                             \
      for (int n = 0; n < 4; ++n)                                                   \
        acc[i][n] =                                                                 \
            __builtin_amdgcn_mfma_f32_16x16x32_fp8_fp8(af[i], bfr[n], acc[i][n], 0, 0, 0); \
    }                                                                               \
    __builtin_amdgcn_s_setprio(0);                                                  \
    __builtin_amdgcn_s_barrier();                                                   \
    _Pragma("unroll")                                                               \
    for (int n = 0; n < 4; ++n) bfr[n] = *(const long*)(Bb_ + brow + n * 1024 + soff1); \
    _Pragma("unroll")                                                               \
    for (int i = 0; i < 4; ++i) af[i] = *(const long*)(Ab_ + arow + i * 1024 + soff1); \
    if (STAGE) gll16(gB + kc_, Bn_ + wv * 1024);                                    \
    __builtin_amdgcn_s_barrier();                                                   \
    asm volatile("s_waitcnt lgkmcnt(0)" ::: "memory");                              \
    __builtin_amdgcn_sched_barrier(0);                                              \
    __builtin_amdgcn_s_setprio(1);                                                  \
    _Pragma("unroll")                                                               \
    for (int i = 0; i < 4; ++i) {                                                   \
      _Pragma("unroll")                                                             \
      for (int n = 0; n < 4; ++n)                                                   \
        acc[i][n] =                                                                 \
            __builtin_amdgcn_mfma_f32_16x16x32_fp8_fp8(af[i], bfr[n], acc[i][n], 0, 0, 0); \
    }                                                                               \
    __builtin_amdgcn_s_setprio(0);                                                  \
    asm volatile("s_waitcnt vmcnt(" #VMN ")" ::: "memory");                         \
    __builtin_amdgcn_s_barrier();                                                   \
    __builtin_amdgcn_sched_barrier(0);                                              \
  }

  // NT = 16 K-tiles (BK=64).  slots cycle kt%3; stage kt+2 -> slot (kt+2)%3.
  for (int kt = 0; kt < 12; kt += 3) {
    DO_TILE(kt + 0, 0, 2, 1, 3);
    DO_TILE(kt + 1, 1, 0, 1, 3);
    DO_TILE(kt + 2, 2, 1, 1, 3);
  }
  DO_TILE(12, 0, 2, 1, 3);
  DO_TILE(13, 1, 0, 1, 3);
  DO_TILE(14, 2, 0, 0, 0);
  DO_TILE(15, 0, 0, 0, 0);
#undef DO_TILE

  const int gr0 = m0 + wr * 64 + lh * 4;
  const int gc0 = n0 + wc * 64 + lr;
  float rs[4][4] = {};
  float ua[16], ub[16];

#define U_LOAD(arr, m)                                                              \
  _Pragma("unroll")                                                                 \
  for (int n = 0; n < 4; ++n)                                                       \
    _Pragma("unroll")                                                               \
    for (int j = 0; j < 4; ++j)                                                     \
      arr[n * 4 + j] = U[(size_t)(gr0 + (m) * 16 + j) * V_DIM + gc0 + n * 16];
#define EPI_M(m, arr)                                                               \
  _Pragma("unroll")                                                                 \
  for (int n = 0; n < 4; ++n) {                                                     \
    const int col = gc0 + n * 16;                                                   \
    _Pragma("unroll")                                                               \
    for (int j = 0; j < 4; ++j) {                                                   \
      const int row = gr0 + (m) * 16 + j;                                           \
      const size_t idx = (size_t)row * V_DIM + col;                                 \
      const float e = __expf(acc[m][n][j] -                                         \
                             2.f * __logf(-__logf(arr[n * 4 + j] + 1e-10f) + 1e-10f)); \
      const short eb = f2bf(e);                                                     \
      Pb[idx] = eb;                                                                 \
      rs[m][j] += bf16f(eb);                                                        \
    }                                                                               \
  }

  U_LOAD(ua, 0);
  U_LOAD(ub, 1);
  EPI_M(0, ua);
  U_LOAD(ua, 2);
  EPI_M(1, ub);
  U_LOAD(ub, 3);
  EPI_M(2, ua);
  EPI_M(3, ub);
#undef U_LOAD
#undef EPI_M

#pragma unroll
  for (int m = 0; m < 4; ++m)
#pragma unroll
    for (int j = 0; j < 4; ++j) {
      float s = rs[m][j];
      s += __shfl_xor(s, 1); s += __shfl_xor(s, 2);
      s += __shfl_xor(s, 4); s += __shfl_xor(s, 8);
      if (lr == 0)
        partials[(size_t)(gr0 + m * 16 + j) * 32 + bx * 2 + wc] = s;
    }
}

// =============== GEMM2 (bf16): 256x256, 4-ring, streamed tokens; invsum
// computed in-prologue from partials (k_rowsum_inv folded in). ---------------
template <int KDIM, int NBX>
__global__ __launch_bounds__(512, 2) void k_gemm8(
    const short* __restrict__ A, const short* __restrict__ B,
    const float* __restrict__ partials, float* __restrict__ C,
    float* __restrict__ tokens, int cpx) {
  __shared__ __align__(16) short Sm[65536];
  __shared__ float invsum_lds[256];
  const int NT = KDIM / 32;
  const int tid = threadIdx.x;
  const int wv = tid >> 6, lane = tid & 63;
  const int lr = lane & 15, lh = lane >> 4;
  const int wr = wv >> 2, wc = wv & 3;
  const int d = blockIdx.x;
  const int L = (d & 7) * cpx + (d >> 3);
  const int by = L / NBX, bx = L % NBX;
  const int m0 = by * 256, n0 = bx * 256;
  const int sg = (((lane & 3) ^ ((lane >> 2) & 3) ^ ((lane >> 4) & 3)) << 3);
  const int srow = wv * 16 + (lane >> 2);
  const short* gA = A + (size_t)(m0 + srow) * KDIM + sg;
  const short* gB = B + (size_t)(n0 + srow) * KDIM + sg;
  const int fslot = lh ^ ((lr ^ (lr >> 2)) & 3);
  const int aoff = wr * 8192 + lr * 64 + fslot * 16;
  const int boff = wc * 4096 + lr * 64 + fslot * 16;

  // ---- invsum for this block's 256 rows: 2 lanes/row, shfl-pair reduce ----
  {
    const int r = tid >> 1;
    const float4* p = (const float4*)&partials[(size_t)(m0 + r) * 32 + (tid & 1) * 16];
    float s = 0.f;
#pragma unroll
    for (int i = 0; i < 4; ++i) { float4 v = p[i]; s += v.x + v.y + v.z + v.w; }
    s += __shfl_xor(s, 1);
    if ((tid & 1) == 0) invsum_lds[r] = 1.f / s;
  }
  __builtin_amdgcn_s_barrier();
  const float inv0 = invsum_lds[srow];
  const float inv1 = invsum_lds[128 + srow];

#pragma unroll
  for (int t = 0; t < 2; ++t) {
#pragma unroll
    for (int q = 0; q < 2; ++q) {
      gll16(gA + (size_t)(q * 128) * KDIM + t * 32, Sm + t * 8192 + q * 4096 + wv * 512);
      gll16(gB + (size_t)(q * 128) * KDIM + t * 32, Sm + 32768 + t * 8192 + q * 4096 + wv * 512);
    }
  }
  asm volatile("s_waitcnt vmcnt(4)" ::: "memory");
  __builtin_amdgcn_s_barrier();
  __builtin_amdgcn_sched_barrier(0);

  floatx4 acc[8][4] = {};

#define DO_TILE(KT, STAGE, VMN, TOKW_)                                              \
  {                                                                                 \
    const int cb_ = (KT) & 3;                                                       \
    const char* Ab_ = (const char*)Sm + cb_ * 16384;                                \
    const char* Bb_ = (const char*)Sm + 65536 + cb_ * 16384;                        \
    short* An_ = Sm + (((KT) + 2) & 3) * 8192;                                      \
    short* Bn_ = Sm + 32768 + (((KT) + 2) & 3) * 8192;                              \
    const size_t kc_ = (size_t)((KT) + 2) * 32;                                     \
    bf16x8 bfr[4], af[4];                                                           \
    _Pragma("unroll")                                                               \
    for (int n = 0; n < 4; ++n) bfr[n] = *(const bf16x8*)(Bb_ + boff + n * 1024);   \
    _Pragma("unroll")                                                               \
    for (int i = 0; i < 4; ++i) af[i] = *(const bf16x8*)(Ab_ + aoff + i * 1024);    \
    if (STAGE) {                                                                    \
      gll16(gA + kc_, An_ + wv * 512);                                              \
      gll16(gA + (size_t)128 * KDIM + kc_, An_ + 4096 + wv * 512);                  \
    }                                                                               \
    __builtin_amdgcn_s_barrier();                                                   \
    asm volatile("s_waitcnt lgkmcnt(0)" ::: "memory");                              \
    __builtin_amdgcn_sched_barrier(0);                                              \
    __builtin_amdgcn_s_setprio(1);                                                  \
    _Pragma("unroll")                                                               \
    for (int i = 0; i < 4; ++i) {                                                   \
      _Pragma("unroll")                                                             \
      for (int n = 0; n < 4; ++n)                                                   \
        acc[i][n] =                                                                 \
            __builtin_amdgcn_mfma_f32_16x16x32_bf16(af[i], bfr[n], acc[i][n], 0, 0, 0); \
    }                                                                               \
    __builtin_amdgcn_s_setprio(0);                                                  \
    __builtin_amdgcn_s_barrier();                                                   \
    _Pragma("unroll")                                                               \
    for (int i = 0; i < 4; ++i)                                                     \
      af[i] = *(const bf16x8*)(Ab_ + aoff + 4096 + i * 1024);                       \
    if (STAGE) {                                                                    \
      gll16(gB + kc_, Bn_ + wv * 512);                                              \
      gll16(gB + (size_t)128 * KDIM + kc_, Bn_ + 4096 + wv * 512);                  \
    }                                                                               \
    __builtin_amdgcn_s_barrier();                                                   \
    asm volatile("s_waitcnt lgkmcnt(0)" ::: "memory");                              \
    __builtin_amdgcn_sched_barrier(0);                                              \
    __builtin_amdgcn_s_setprio(1);                                                  \
    _Pragma("unroll")                                                               \
    for (int i = 0; i < 4; ++i) {                                                   \
      _Pragma("unroll")                                                             \
      for (int n = 0; n < 4; ++n)                                                   \
        acc[4 + i][n] =                                                             \
            __builtin_amdgcn_mfma_f32_16x16x32_bf16(af[i], bfr[n], acc[4 + i][n], 0, 0, 0); \
    }                                                                               \
    __builtin_amdgcn_s_setprio(0);                                                  \
    if (TOKW_) {                                                                    \
      const short* myA_ = Sm + cb_ * 8192 + wv * 512 + lane * 8;                    \
      const bf16x8 v0_ = *(const bf16x8*)myA_;                                      \
      const bf16x8 v1_ = *(const bf16x8*)(myA_ + 4096);                             \
      const size_t c0_ = (size_t)(KT) * 32 + sg;                                    \
      float4 a_, b_;                                                                \
      a_.x = bf16f(v0_[0]) * inv0; a_.y = bf16f(v0_[1]) * inv0;                     \
      a_.z = bf16f(v0_[2]) * inv0; a_.w = bf16f(v0_[3]) * inv0;                     \
      b_.x = bf16f(v0_[4]) * inv0; b_.y = bf16f(v0_[5]) * inv0;                     \
      b_.z = bf16f(v0_[6]) * inv0; b_.w = bf16f(v0_[7]) * inv0;                     \
      *(float4*)&tokens[(size_t)(m0 + srow) * KDIM + c0_] = a_;                     \
      *(float4*)&tokens[(size_t)(m0 + srow) * KDIM + c0_ + 4] = b_;                 \
      a_.x = bf16f(v1_[0]) * inv1; a_.y = bf16f(v1_[1]) * inv1;                     \
      a_.z = bf16f(v1_[2]) * inv1; a_.w = bf16f(v1_[3]) * inv1;                     \
      b_.x = bf16f(v1_[4]) * inv1; b_.y = bf16f(v1_[5]) * inv1;                     \
      b_.z = bf16f(v1_[6]) * inv1; b_.w = bf16f(v1_[7]) * inv1;                     \
      *(float4*)&tokens[(size_t)(m0 + 128 + srow) * KDIM + c0_] = a_;               \
      *(float4*)&tokens[(size_t)(m0 + 128 + srow) * KDIM + c0_ + 4] = b_;           \
    }                                                                               \
    asm volatile("s_waitcnt vmcnt(" #VMN ")" ::: "memory");                         \
    __builtin_amdgcn_s_barrier();                                                   \
    __builtin_amdgcn_sched_barrier(0);                                              \
  }

  {
    const int s = bx * 16;
    int kt = 0;
    for (; kt < s; ++kt) DO_TILE(kt, 1, 4, 0);
    DO_TILE(kt, 1, 8, 1);
    ++kt;
    for (; kt < s + 16 && kt < NT - 2; ++kt) DO_TILE(kt, 1, 12, 1);
    if (kt == s + 16) {
      DO_TILE(kt, 1, 8, 0);
      ++kt;
    }
    for (; kt < NT - 2; ++kt) DO_TILE(kt, 1, 4, 0);
    DO_TILE(NT - 2, 0, 0, ((NT - 2) >> 4) == bx);
    DO_TILE(NT - 1, 0, 0, ((NT - 1) >> 4) == bx);
  }
#undef DO_TILE

  const int gr0 = m0 + wr * 128 + lh * 4;
  const int gc0 = n0 + wc * 64 + lr;
#pragma unroll
  for (int m = 0; m < 8; ++m)
#pragma unroll
    for (int j = 0; j < 4; ++j) {
      const int row = gr0 + m * 16 + j;
      const float s = invsum_lds[row - m0];
#pragma unroll
      for (int n = 0; n < 4; ++n)
        C[(size_t)row * E_DIM + gc0 + n * 16] = acc[m][n][j] * s;
    }
}

// =============== FALLBACK PATH (round-1, known-correct) ======================
__global__ __launch_bounds__(256) void k_gemm_nt(const short* __restrict__ A,
                                                 const short* __restrict__ B,
                                                 float* __restrict__ C,
                                                 int lda, int ldb, int ldc, int K) {
  __shared__ __align__(16) short As[128][64];
  __shared__ __align__(16) short Bs[128][64];
  const int t = threadIdx.x;
  const int w = t >> 6, l = t & 63;
  const int lr = l & 15, lh = l >> 4;
  const int m0 = blockIdx.y * 128, n0 = blockIdx.x * 128;
  const int wm = (w >> 1) * 64, wn = (w & 1) * 64;
  floatx4 acc[4][4] = {};
  for (int k0 = 0; k0 < K; k0 += 64) {
    __syncthreads();
#pragma unroll
    for (int i = 0; i < 4; ++i) {
      const int c = i * 256 + t;
      const int r = c >> 3, c8 = (c & 7) * 8;
      *(bf16x8*)&As[r][c8] = *(const bf16x8*)&A[(size_t)(m0 + r) * lda + k0 + c8];
      *(bf16x8*)&Bs[r][c8] = *(const bf16x8*)&B[(size_t)(n0 + r) * ldb + k0 + c8];
    }
    __syncthreads();
#pragma unroll
    for (int kk = 0; kk < 64; kk += 32) {
      bf16x8 af[4], bfr[4];
#pragma unroll
      for (int m = 0; m < 4; ++m) af[m] = *(const bf16x8*)&As[wm + m * 16 + lr][kk + lh * 8];
#pragma unroll
      for (int n = 0; n < 4; ++n) bfr[n] = *(const bf16x8*)&Bs[wn + n * 16 + lr][kk + lh * 8];
#pragma unroll
      for (int m = 0; m < 4; ++m)
#pragma unroll
        for (int n = 0; n < 4; ++n)
          acc[m][n] = __builtin_amdgcn_mfma_f32_16x16x32_bf16(af[m], bfr[n], acc[m][n], 0, 0, 0);
    }
  }
#pragma unroll
  for (int m = 0; m < 4; ++m)
#pragma unroll
    for (int n = 0; n < 4; ++n) {
      const int col = n0 + wn + n * 16 + lr;
#pragma unroll
      for (int j = 0; j < 4; ++j)
        C[(size_t)(m0 + wm + m * 16 + lh * 4 + j) * ldc + col] = acc[m][n][j];
    }
}

__global__ __launch_bounds__(256) void k_gemm_nt_f32a(const float* __restrict__ A,
                                                      const short* __restrict__ B,
                                                      float* __restrict__ C,
                                                      int lda, int ldb, int ldc, int K) {
  __shared__ __align__(16) short As[128][64];
  __shared__ __align__(16) short Bs[128][64];
  const int t = threadIdx.x;
  const int w = t >> 6, l = t & 63;
  const int lr = l & 15, lh = l >> 4;
  const int m0 = blockIdx.y * 128, n0 = blockIdx.x * 128;
  const int wm = (w >> 1) * 64, wn = (w & 1) * 64;
  floatx4 acc[4][4] = {};
  for (int k0 = 0; k0 < K; k0 += 64) {
    __syncthreads();
#pragma unroll
    for (int i = 0; i < 4; ++i) {
      const int c = i * 256 + t;
      const int r = c >> 3, c8 = (c & 7) * 8;
      const float4 a0 = *(const float4*)&A[(size_t)(m0 + r) * lda + k0 + c8];
      const float4 a1 = *(const float4*)&A[(size_t)(m0 + r) * lda + k0 + c8 + 4];
      bf16x8 va;
      va[0] = f2bf(a0.x); va[1] = f2bf(a0.y); va[2] = f2bf(a0.z); va[3] = f2bf(a0.w);
      va[4] = f2bf(a1.x); va[5] = f2bf(a1.y); va[6] = f2bf(a1.z); va[7] = f2bf(a1.w);
      *(bf16x8*)&As[r][c8] = va;
      *(bf16x8*)&Bs[r][c8] = *(const bf16x8*)&B[(size_t)(n0 + r) * ldb + k0 + c8];
    }
    __syncthreads();
#pragma unroll
    for (int kk = 0; kk < 64; kk += 32) {
      bf16x8 af[4], bfr[4];
#pragma unroll
      for (int m = 0; m < 4; ++m) af[m] = *(const bf16x8*)&As[wm + m * 16 + lr][kk + lh * 8];
#pragma unroll
      for (int n = 0; n < 4; ++n) bfr[n] = *(const bf16x8*)&Bs[wn + n * 16 + lr][kk + lh * 8];
#pragma unroll
      for (int m = 0; m < 4; ++m)
#pragma unroll
        for (int n = 0; n < 4; ++n)
          acc[m][n] = __builtin_amdgcn_mfma_f32_16x16x32_bf16(af[m], bfr[n], acc[m][n], 0, 0, 0);
    }
  }
#pragma unroll
  for (int m = 0; m < 4; ++m)
#pragma unroll
    for (int n = 0; n < 4; ++n) {
      const int col = n0 + wn + n * 16 + lr;
#pragma unroll
      for (int j = 0; j < 4; ++j)
        C[(size_t)(m0 + wm + m * 16 + lh * 4 + j) * ldc + col] = acc[m][n][j];
    }
}

__global__ __launch_bounds__(256) void k_gumbel_softmax(float* __restrict__ S,
                                                        const float* __restrict__ U) {
  const int t = threadIdx.x;
  const int w = t >> 6, l = t & 63;
  const size_t base = (size_t)blockIdx.x * V_DIM + t * 8;
  const float4 s0 = *(const float4*)&S[base];
  const float4 s1 = *(const float4*)&S[base + 4];
  const float4 u0 = *(const float4*)&U[base];
  const float4 u1 = *(const float4*)&U[base + 4];
  float x[8];
  x[0] = s0.x - 2.f * __logf(-__logf(u0.x + 1e-10f) + 1e-10f);
  x[1] = s0.y - 2.f * __logf(-__logf(u0.y + 1e-10f) + 1e-10f);
  x[2] = s0.z - 2.f * __logf(-__logf(u0.z + 1e-10f) + 1e-10f);
  x[3] = s0.w - 2.f * __logf(-__logf(u0.w + 1e-10f) + 1e-10f);
  x[4] = s1.x - 2.f * __logf(-__logf(u1.x + 1e-10f) + 1e-10f);
  x[5] = s1.y - 2.f * __logf(-__logf(u1.y + 1e-10f) + 1e-10f);
  x[6] = s1.z - 2.f * __logf(-__logf(u1.z + 1e-10f) + 1e-10f);
  x[7] = s1.w - 2.f * __logf(-__logf(u1.w + 1e-10f) + 1e-10f);
  float lm = x[0];
#pragma unroll
  for (int i = 1; i < 8; ++i) lm = fmaxf(lm, x[i]);
  lm = wave_max(lm);
  __shared__ float redA[4], redB[4];
  if (l == 0) redA[w] = lm;
  __syncthreads();
  const float m = fmaxf(fmaxf(redA[0], redA[1]), fmaxf(redA[2], redA[3]));
  float p[8];
  float ls = 0.f;
#pragma unroll
  for (int i = 0; i < 8; ++i) { p[i] = __expf(x[i] - m); ls += p[i]; }
  ls = wave_sum(ls);
  if (l == 0) redB[w] = ls;
  __syncthreads();
  const float inv = 1.0f / (redB[0] + redB[1] + redB[2] + redB[3]);
  float4 o0 = make_float4(p[0] * inv, p[1] * inv, p[2] * inv, p[3] * inv);
  float4 o1 = make_float4(p[4] * inv, p[5] * inv, p[6] * inv, p[7] * inv);
  *(float4*)&S[base] = o0;
  *(float4*)&S[base + 4] = o1;
}

extern "C" void kernel_launch(void* const* d_in, const int* in_sizes, int n_in,
                              void* d_out, int out_size, void* d_ws, size_t ws_size,
                              hipStream_t stream) {
  const float* z = (const float*)d_in[0];
  const float* W = (const float*)d_in[1];
  const float* U = (const float*)d_in[2];
  float* tokens = (float*)d_out;                    // [N, V] f32
  float* zq = tokens + (size_t)N_ROWS * V_DIM;      // [N, E] f32
  short* zn = (short*)zq;                           // bf16 zn in z_q region (fallback)
  unsigned char* zn8 =                              // fp8 zn (64 MB)
      (unsigned char*)zq + (size_t)N_ROWS * E_DIM * 2;

  short* embn = (short*)d_ws;                            // 4 MB (fallback)
  short* embnT = embn + (size_t)V_DIM * E_DIM;           // 4 MB
  unsigned char* embn8 = (unsigned char*)(embnT + (size_t)V_DIM * E_DIM);  // 2 MB

  const size_t NEED = (size_t)V_DIM * E_DIM * 2 * 2     // embn + embnT
                    + (size_t)V_DIM * E_DIM             // embn8
                    + (size_t)N_ROWS * 32 * 4           // partials (8 MB)
                    + (size_t)N_ROWS * 4                // (spare)
                    + (size_t)N_ROWS * V_DIM * 2;       // P~ bf16 (256 MB)

  if (ws_size >= NEED) {
    float* partials = (float*)(embn8 + (size_t)V_DIM * E_DIM);
    float* spare = partials + (size_t)N_ROWS * 32;
    short* Pb = (short*)(spare + N_ROWS);
    // merged norms (fast: skip bf16 zn/embn stores)
    k_norm_all<1><<<V_DIM + N_ROWS / 4, 256, 0, stream>>>(
        z, W, zn, zn8, embn, embnT, embn8);
    // GEMM1 fp8 fused gumbel-exp: grid = (65536/256) * (2048/128) = 4096
    k_gemm_f8<<<4096, 512, 0, stream>>>(zn8, embn8, U, Pb, partials, 4096 / 8);
    // GEMM2 bf16 scaled + streamed tokens + in-prologue invsum: grid = 1024
    k_gemm8<V_DIM, 4><<<1024, 512, 0, stream>>>(
        Pb, embnT, partials, zq, tokens, 1024 / 8);
  } else {
    k_norm_all<0><<<V_DIM + N_ROWS / 4, 256, 0, stream>>>(
        z, W, zn, zn8, embn, embnT, embn8);
    k_gemm_nt<<<dim3(V_DIM / 128, N_ROWS / 128), 256, 0, stream>>>(
        zn, embn, tokens, E_DIM, E_DIM, V_DIM, E_DIM);
    k_gumbel_softmax<<<N_ROWS, 256, 0, stream>>>(tokens, U);
    k_gemm_nt_f32a<<<dim3(E_DIM / 128, N_ROWS / 128), 256, 0, stream>>>(
        tokens, embnT, zq, V_DIM, V_DIM, E_DIM, V_DIM);
  }
}

// Round 18
// 845.892 us; speedup vs baseline: 1.0682x; 1.0682x over previous
//
#include <hip/hip_runtime.h>
#include <hip/hip_bf16.h>
#include <stdint.h>

typedef short bf16x8 __attribute__((ext_vector_type(8)));
typedef float floatx4 __attribute__((ext_vector_type(4)));

#define N_ROWS 65536
#define V_DIM 2048
#define E_DIM 1024

__device__ __forceinline__ short f2bf(float x) {
  union { float f; uint32_t u; } c; c.f = x;
  uint32_t r = (c.u + 0x7FFFu + ((c.u >> 16) & 1u)) >> 16;
  return (short)(uint16_t)r;
}
__device__ __forceinline__ float bf16f(short b) {
  union { uint32_t u; float f; } c; c.u = ((uint32_t)(uint16_t)b) << 16;
  return c.f;
}
// f32 -> OCP e4m3fn (RNE); values here are < 2.2, clamps for safety.
__device__ __forceinline__ uint32_t f2e4m3(float x) {
  union { float f; uint32_t u; } c; c.f = x;
  const uint32_t s = (c.u >> 24) & 0x80u;
  float ax = fabsf(x);
  uint32_t code;
  if (ax < 0.015625f) {                       // below min normal 2^-6
    code = (uint32_t)__float2int_rn(ax * 512.0f);   // 0..8 (8 == 2^-6 normal)
  } else {
    c.f = ax;
    uint32_t r = c.u + 0x7FFFFu + ((c.u >> 20) & 1u);
    code = (r >> 20) - (120u << 3);
    if (code > 0x7Eu) code = 0x7Eu;
  }
  return s | code;
}

__device__ __forceinline__ float wave_sum(float v) {
#pragma unroll
  for (int o = 32; o > 0; o >>= 1) v += __shfl_xor(v, o);
  return v;
}
__device__ __forceinline__ float wave_max(float v) {
#pragma unroll
  for (int o = 32; o > 0; o >>= 1) v = fmaxf(v, __shfl_xor(v, o));
  return v;
}

__device__ __forceinline__ void gll16(const void* g, void* l) {
  __builtin_amdgcn_global_load_lds(
      (const __attribute__((address_space(1))) void*)g,
      (__attribute__((address_space(3))) void*)l, 16, 0, 0);
}

// ---------------- merged normalize: blocks [0,V_DIM) do emb rows; the rest do
// z rows (4 rows/block).  FAST=1 skips the bf16 copies only the fallback uses.
template <int FAST>
__global__ __launch_bounds__(256) void k_norm_all(
    const float* __restrict__ Z, const float* __restrict__ W,
    short* __restrict__ zn, unsigned char* __restrict__ zn8,
    short* __restrict__ embn, short* __restrict__ embnT,
    unsigned char* __restrict__ embn8) {
  const int t = threadIdx.x;
  const int w = t >> 6, l = t & 63;
  if (blockIdx.x < V_DIM) {
    const int v = blockIdx.x;
    const float4 val = *(const float4*)&W[(size_t)v * E_DIM + t * 4];
    float ss = val.x * val.x + val.y * val.y + val.z * val.z + val.w * val.w;
    ss = wave_sum(ss);
    __shared__ float red[4];
    if (l == 0) red[w] = ss;
    __syncthreads();
    ss = red[0] + red[1] + red[2] + red[3];
    const float inv = 1.0f / fmaxf(sqrtf(ss), 1e-12f);
    short4 o;
    o.x = f2bf(val.x * inv);
    o.y = f2bf(val.y * inv);
    o.z = f2bf(val.z * inv);
    o.w = f2bf(val.w * inv);
    if (!FAST) *(short4*)&embn[(size_t)v * E_DIM + t * 4] = o;
    embnT[(size_t)(t * 4 + 0) * V_DIM + v] = o.x;
    embnT[(size_t)(t * 4 + 1) * V_DIM + v] = o.y;
    embnT[(size_t)(t * 4 + 2) * V_DIM + v] = o.z;
    embnT[(size_t)(t * 4 + 3) * V_DIM + v] = o.w;
    const uint32_t p = f2e4m3(val.x * inv) | (f2e4m3(val.y * inv) << 8) |
                       (f2e4m3(val.z * inv) << 16) | (f2e4m3(val.w * inv) << 24);
    *(uint32_t*)&embn8[(size_t)v * E_DIM + t * 4] = p;
  } else {
    const int row = (blockIdx.x - V_DIM) * 4 + w;
    const float* zr = Z + (size_t)row * E_DIM;
    float4 v[4];
    float ss = 0.f;
#pragma unroll
    for (int i = 0; i < 4; ++i) {
      v[i] = *(const float4*)&zr[(i * 64 + l) * 4];
      ss += v[i].x * v[i].x + v[i].y * v[i].y + v[i].z * v[i].z + v[i].w * v[i].w;
    }
    ss = wave_sum(ss);
    const float SCALE = 2.0f * (expf(-2.995732273553991f) + 1.0f);  // kappa_q / T
    const float inv = SCALE / fmaxf(sqrtf(ss), 1e-12f);
    unsigned char* zo8 = zn8 + (size_t)row * E_DIM;
#pragma unroll
    for (int i = 0; i < 4; ++i) {
      if (!FAST) {
        short4 o;
        o.x = f2bf(v[i].x * inv);
        o.y = f2bf(v[i].y * inv);
        o.z = f2bf(v[i].z * inv);
        o.w = f2bf(v[i].w * inv);
        *(short4*)&zn[(size_t)row * E_DIM + (i * 64 + l) * 4] = o;
      }
      const uint32_t p = f2e4m3(v[i].x * inv) | (f2e4m3(v[i].y * inv) << 8) |
                         (f2e4m3(v[i].z * inv) << 16) | (f2e4m3(v[i].w * inv) << 24);
      *(uint32_t*)&zo8[(i * 64 + l) * 4] = p;
    }
  }
}

// =============== GEMM1 (fp8): 256x128 tile, BK=64, ring-3 (72 KiB LDS),
// 2 blocks/CU (launch_bounds(512,4), acc=64 regs/wave): one block's BW-bound
// gumbel-exp epilogue overlaps the sibling block's MFMA mainloop.
// Swizzle: 64B rows, 16B chunks, chunk ^= row&3 (source AND read sides).
__global__ __launch_bounds__(512, 4) void k_gemm_f8(
    const unsigned char* __restrict__ A8, const unsigned char* __restrict__ B8,
    const float* __restrict__ U, short* __restrict__ Pb,
    float* __restrict__ partials, int cpx) {
  __shared__ __align__(16) char Sm[73728];  // A ring: 3 x 16KB at 0; B ring: 3 x 8KB at 49152
  const int tid = threadIdx.x;
  const int wv = tid >> 6, lane = tid & 63;
  const int lr = lane & 15, lh = lane >> 4;
  const int wr = wv >> 1, wc = wv & 1;      // 4x2 wave grid (64x64 per wave)
  const int d = blockIdx.x;
  const int L = (d & 7) * cpx + (d >> 3);
  const int by = L >> 4, bx = L & 15;       // 256 x 16 tiles, row-major
  const int m0 = by * 256, n0 = bx * 128;
  // staging: thread covers 16B chunk (tid&3) of LDS row (tid>>2); linear dest;
  // source chunk pre-swizzled: src_chunk = (tid&3) ^ ((tid>>2)&3)
  const int sg8 = (((tid & 3) ^ ((tid >> 2) & 3)) << 4);
  const unsigned char* gA = A8 + (size_t)(m0 + (tid >> 2)) * E_DIM + sg8;
  const unsigned char* gB = B8 + (size_t)(n0 + (tid >> 2)) * E_DIM + sg8;
  // fragment reads: row = band + m*16 + lr (row&3 = lr&3); k-step s granule
  // g = lh + 4s -> chunk = (lh>>1) + 2s, half = lh&1; read chunk' = chunk^(lr&3)
  const int t3 = lr & 3;
  const int soff0 = ((((lh >> 1) + 0) ^ t3) << 4) + (lh & 1) * 8;
  const int soff1 = ((((lh >> 1) + 2) ^ t3) << 4) + (lh & 1) * 8;
  const int arow = (wr * 64 + lr) * 64;   // byte base of A frag rows in slot
  const int brow = (wc * 64 + lr) * 64;   // byte base of B frag rows in slot

  // prologue: stage tiles 0 (slot0) and 1 (slot1), 3 loads each
#pragma unroll
  for (int t = 0; t < 2; ++t) {
    char* sa = Sm + t * 16384;
    char* sb = Sm + 49152 + t * 8192;
    gll16(gA + t * 64, sa + wv * 1024);
    gll16(gA + (size_t)128 * E_DIM + t * 64, sa + 8192 + wv * 1024);
    gll16(gB + t * 64, sb + wv * 1024);
  }
  asm volatile("s_waitcnt vmcnt(3)" ::: "memory");
  __builtin_amdgcn_s_barrier();
  __builtin_amdgcn_sched_barrier(0);

  floatx4 acc[4][4] = {};

#define DO_TILE(KT, CB, SN, STAGE, VMN)                                             \
  {                                                                                 \
    const char* Ab_ = Sm + (CB) * 16384;                                            \
    const char* Bb_ = Sm + 49152 + (CB) * 8192;                                     \
    char* An_ = Sm + (SN) * 16384;                                                  \
    char* Bn_ = Sm + 49152 + (SN) * 8192;                                           \
    const size_t kc_ = (size_t)((KT) + 2) * 64;                                     \
    long bfr[4], af[4];                                                             \
    /* ---- phase A: frags k-step 0 | stage A-lo + A-hi of kt+2 ---- */            \
    _Pragma("unroll")                                                               \
    for (int n = 0; n < 4; ++n) bfr[n] = *(const long*)(Bb_ + brow + n * 1024 + soff0); \
    _Pragma("unroll")                                                               \
    for (int i = 0; i < 4; ++i) af[i] = *(const long*)(Ab_ + arow + i * 1024 + soff0); \
    if (STAGE) {                                                                    \
      gll16(gA + kc_, An_ + wv * 1024);                                             \
      gll16(gA + (size_t)128 * E_DIM + kc_, An_ + 8192 + wv * 1024);                \
    }                                                                               \
    __builtin_amdgcn_s_barrier();                                                   \
    asm volatile("s_waitcnt lgkmcnt(0)" ::: "memory");                              \
    __builtin_amdgcn_sched_barrier(0);                                              \
    __builtin_amdgcn_s_setprio(1);                                                  \
    _Pragma("unroll")                                                               \
    for (int i = 0; i < 4; ++i) {                                                   \
      _Pragma("unroll")                                                             \
      for (int n = 0; n < 4; ++n)                                                   \
        acc[i][n] =                                                                 \
            __builtin_amdgcn_mfma_f32_16x16x32_fp8_fp8(af[i], bfr[n], acc[i][n], 0, 0, 0); \
    }                                                                               \
    __builtin_amdgcn_s_setprio(0);                                                  \
    __builtin_amdgcn_s_barrier();                                                   \
    /* ---- phase B: frags k-step 1 | stage B of kt+2 ---- */                       \
    _Pragma("unroll")                                                               \
    for (int n = 0; n < 4; ++n) bfr[n] = *(const long*)(Bb_ + brow + n * 1024 + soff1); \
    _Pragma("unroll")                                                               \
    for (int i = 0; i < 4; ++i) af[i] = *(const long*)(Ab_ + arow + i * 1024 + soff1); \
    if (STAGE) gll16(gB + kc_, Bn_ + wv * 1024);                                    \
    __builtin_amdgcn_s_barrier();                                                   \
    asm volatile("s_waitcnt lgkmcnt(0)" ::: "memory");                              \
    __builtin_amdgcn_sched_barrier(0);                                              \
    __builtin_amdgcn_s_setprio(1);                                                  \
    _Pragma("unroll")                                                               \
    for (int i = 0; i < 4; ++i) {                                                   \
      _Pragma("unroll")                                                             \
      for (int n = 0; n < 4; ++n)                                                   \
        acc[i][n] =                                                                 \
            __builtin_amdgcn_mfma_f32_16x16x32_fp8_fp8(af[i], bfr[n], acc[i][n], 0, 0, 0); \
    }                                                                               \
    __builtin_amdgcn_s_setprio(0);                                                  \
    asm volatile("s_waitcnt vmcnt(" #VMN ")" ::: "memory");                         \
    __builtin_amdgcn_s_barrier();                                                   \
    __builtin_amdgcn_sched_barrier(0);                                              \
  }

  // NT = 16 K-tiles (BK=64).  slots cycle kt%3; stage kt+2 -> slot (kt+2)%3.
  for (int kt = 0; kt < 12; kt += 3) {
    DO_TILE(kt + 0, 0, 2, 1, 3);
    DO_TILE(kt + 1, 1, 0, 1, 3);
    DO_TILE(kt + 2, 2, 1, 1, 3);
  }
  DO_TILE(12, 0, 2, 1, 3);
  DO_TILE(13, 1, 0, 1, 3);
  DO_TILE(14, 2, 0, 0, 0);
  DO_TILE(15, 0, 0, 0, 0);
#undef DO_TILE

  const int gr0 = m0 + wr * 64 + lh * 4;
  const int gc0 = n0 + wc * 64 + lr;
  float rs[4][4] = {};
#pragma unroll
  for (int m = 0; m < 4; ++m)
#pragma unroll
    for (int n = 0; n < 4; ++n) {
      const int col = gc0 + n * 16;
#pragma unroll
      for (int j = 0; j < 4; ++j) {
        const int row = gr0 + m * 16 + j;
        const size_t idx = (size_t)row * V_DIM + col;
        const float u = U[idx];
        const float e = __expf(acc[m][n][j] - 2.f * __logf(-__logf(u + 1e-10f) + 1e-10f));
        const short eb = f2bf(e);
        Pb[idx] = eb;
        rs[m][j] += bf16f(eb);
      }
    }
#pragma unroll
  for (int m = 0; m < 4; ++m)
#pragma unroll
    for (int j = 0; j < 4; ++j) {
      float s = rs[m][j];
      s += __shfl_xor(s, 1); s += __shfl_xor(s, 2);
      s += __shfl_xor(s, 4); s += __shfl_xor(s, 8);
      if (lr == 0)
        partials[(size_t)(gr0 + m * 16 + j) * 32 + bx * 2 + wc] = s;
    }
}

// =============== GEMM2 (bf16, R12 form): 256x256, 4-ring, streamed tokens ----
template <int KDIM, int NBX>
__global__ __launch_bounds__(512, 2) void k_gemm8(
    const short* __restrict__ A, const short* __restrict__ B,
    const float* __restrict__ invsum, float* __restrict__ C,
    float* __restrict__ tokens, int cpx) {
  __shared__ __align__(16) short Sm[65536];
  const int NT = KDIM / 32;
  const int tid = threadIdx.x;
  const int wv = tid >> 6, lane = tid & 63;
  const int lr = lane & 15, lh = lane >> 4;
  const int wr = wv >> 2, wc = wv & 3;
  const int d = blockIdx.x;
  const int L = (d & 7) * cpx + (d >> 3);
  const int by = L / NBX, bx = L % NBX;
  const int m0 = by * 256, n0 = bx * 256;
  const int sg = (((lane & 3) ^ ((lane >> 2) & 3) ^ ((lane >> 4) & 3)) << 3);
  const int srow = wv * 16 + (lane >> 2);
  const short* gA = A + (size_t)(m0 + srow) * KDIM + sg;
  const short* gB = B + (size_t)(n0 + srow) * KDIM + sg;
  const int fslot = lh ^ ((lr ^ (lr >> 2)) & 3);
  const int aoff = wr * 8192 + lr * 64 + fslot * 16;
  const int boff = wc * 4096 + lr * 64 + fslot * 16;

  float inv0 = invsum[m0 + srow];
  float inv1 = invsum[m0 + 128 + srow];

#pragma unroll
  for (int t = 0; t < 2; ++t) {
#pragma unroll
    for (int q = 0; q < 2; ++q) {
      gll16(gA + (size_t)(q * 128) * KDIM + t * 32, Sm + t * 8192 + q * 4096 + wv * 512);
      gll16(gB + (size_t)(q * 128) * KDIM + t * 32, Sm + 32768 + t * 8192 + q * 4096 + wv * 512);
    }
  }
  asm volatile("s_waitcnt vmcnt(4)" ::: "memory");
  __builtin_amdgcn_s_barrier();
  __builtin_amdgcn_sched_barrier(0);

  floatx4 acc[8][4] = {};

#define DO_TILE(KT, STAGE, VMN, TOKW_)                                              \
  {                                                                                 \
    const int cb_ = (KT) & 3;                                                       \
    const char* Ab_ = (const char*)Sm + cb_ * 16384;                                \
    const char* Bb_ = (const char*)Sm + 65536 + cb_ * 16384;                        \
    short* An_ = Sm + (((KT) + 2) & 3) * 8192;                                      \
    short* Bn_ = Sm + 32768 + (((KT) + 2) & 3) * 8192;                              \
    const size_t kc_ = (size_t)((KT) + 2) * 32;                                     \
    bf16x8 bfr[4], af[4];                                                           \
    _Pragma("unroll")                                                               \
    for (int n = 0; n < 4; ++n) bfr[n] = *(const bf16x8*)(Bb_ + boff + n * 1024);   \
    _Pragma("unroll")                                                               \
    for (int i = 0; i < 4; ++i) af[i] = *(const bf16x8*)(Ab_ + aoff + i * 1024);    \
    if (STAGE) {                                                                    \
      gll16(gA + kc_, An_ + wv * 512);                                              \
      gll16(gA + (size_t)128 * KDIM + kc_, An_ + 4096 + wv * 512);                  \
    }                                                                               \
    __builtin_amdgcn_s_barrier();                                                   \
    asm volatile("s_waitcnt lgkmcnt(0)" ::: "memory");                              \
    __builtin_amdgcn_sched_barrier(0);                                              \
    __builtin_amdgcn_s_setprio(1);                                                  \
    _Pragma("unroll")                                                               \
    for (int i = 0; i < 4; ++i) {                                                   \
      _Pragma("unroll")                                                             \
      for (int n = 0; n < 4; ++n)                                                   \
        acc[i][n] =                                                                 \
            __builtin_amdgcn_mfma_f32_16x16x32_bf16(af[i], bfr[n], acc[i][n], 0, 0, 0); \
    }                                                                               \
    __builtin_amdgcn_s_setprio(0);                                                  \
    __builtin_amdgcn_s_barrier();                                                   \
    _Pragma("unroll")                                                               \
    for (int i = 0; i < 4; ++i)                                                     \
      af[i] = *(const bf16x8*)(Ab_ + aoff + 4096 + i * 1024);                       \
    if (STAGE) {                                                                    \
      gll16(gB + kc_, Bn_ + wv * 512);                                              \
      gll16(gB + (size_t)128 * KDIM + kc_, Bn_ + 4096 + wv * 512);                  \
    }                                                                               \
    __builtin_amdgcn_s_barrier();                                                   \
    asm volatile("s_waitcnt lgkmcnt(0)" ::: "memory");                              \
    __builtin_amdgcn_sched_barrier(0);                                              \
    __builtin_amdgcn_s_setprio(1);                                                  \
    _Pragma("unroll")                                                               \
    for (int i = 0; i < 4; ++i) {                                                   \
      _Pragma("unroll")                                                             \
      for (int n = 0; n < 4; ++n)                                                   \
        acc[4 + i][n] =                                                             \
            __builtin_amdgcn_mfma_f32_16x16x32_bf16(af[i], bfr[n], acc[4 + i][n], 0, 0, 0); \
    }                                                                               \
    __builtin_amdgcn_s_setprio(0);                                                  \
    if (TOKW_) {                                                                    \
      const short* myA_ = Sm + cb_ * 8192 + wv * 512 + lane * 8;                    \
      const bf16x8 v0_ = *(const bf16x8*)myA_;                                      \
      const bf16x8 v1_ = *(const bf16x8*)(myA_ + 4096);                             \
      const size_t c0_ = (size_t)(KT) * 32 + sg;                                    \
      float4 a_, b_;                                                                \
      a_.x = bf16f(v0_[0]) * inv0; a_.y = bf16f(v0_[1]) * inv0;                     \
      a_.z = bf16f(v0_[2]) * inv0; a_.w = bf16f(v0_[3]) * inv0;                     \
      b_.x = bf16f(v0_[4]) * inv0; b_.y = bf16f(v0_[5]) * inv0;                     \
      b_.z = bf16f(v0_[6]) * inv0; b_.w = bf16f(v0_[7]) * inv0;                     \
      *(float4*)&tokens[(size_t)(m0 + srow) * KDIM + c0_] = a_;                     \
      *(float4*)&tokens[(size_t)(m0 + srow) * KDIM + c0_ + 4] = b_;                 \
      a_.x = bf16f(v1_[0]) * inv1; a_.y = bf16f(v1_[1]) * inv1;                     \
      a_.z = bf16f(v1_[2]) * inv1; a_.w = bf16f(v1_[3]) * inv1;                     \
      b_.x = bf16f(v1_[4]) * inv1; b_.y = bf16f(v1_[5]) * inv1;                     \
      b_.z = bf16f(v1_[6]) * inv1; b_.w = bf16f(v1_[7]) * inv1;                     \
      *(float4*)&tokens[(size_t)(m0 + 128 + srow) * KDIM + c0_] = a_;               \
      *(float4*)&tokens[(size_t)(m0 + 128 + srow) * KDIM + c0_ + 4] = b_;           \
    }                                                                               \
    asm volatile("s_waitcnt vmcnt(" #VMN ")" ::: "memory");                         \
    __builtin_amdgcn_s_barrier();                                                   \
    __builtin_amdgcn_sched_barrier(0);                                              \
  }

  {
    const int s = bx * 16;
    int kt = 0;
    for (; kt < s; ++kt) DO_TILE(kt, 1, 4, 0);
    DO_TILE(kt, 1, 8, 1);
    ++kt;
    for (; kt < s + 16 && kt < NT - 2; ++kt) DO_TILE(kt, 1, 12, 1);
    if (kt == s + 16) {
      DO_TILE(kt, 1, 8, 0);
      ++kt;
    }
    for (; kt < NT - 2; ++kt) DO_TILE(kt, 1, 4, 0);
    DO_TILE(NT - 2, 0, 0, ((NT - 2) >> 4) == bx);
    DO_TILE(NT - 1, 0, 0, ((NT - 1) >> 4) == bx);
  }
#undef DO_TILE

  const int gr0 = m0 + wr * 128 + lh * 4;
  const int gc0 = n0 + wc * 64 + lr;
#pragma unroll
  for (int m = 0; m < 8; ++m)
#pragma unroll
    for (int j = 0; j < 4; ++j) {
      const int row = gr0 + m * 16 + j;
      const float s = invsum[row];
#pragma unroll
      for (int n = 0; n < 4; ++n)
        C[(size_t)row * E_DIM + gc0 + n * 16] = acc[m][n][j] * s;
    }
}

// invsum[r] = 1 / sum(partials[r][0..32))
__global__ __launch_bounds__(256) void k_rowsum_inv(const float* __restrict__ partials,
                                                    float* __restrict__ invsum) {
  const int r = blockIdx.x * 256 + threadIdx.x;
  const float4* p = (const float4*)&partials[(size_t)r * 32];
  float s = 0.f;
#pragma unroll
  for (int i = 0; i < 8; ++i) { float4 v = p[i]; s += v.x + v.y + v.z + v.w; }
  invsum[r] = 1.f / s;
}

// =============== FALLBACK PATH (round-1, known-correct) ======================
__global__ __launch_bounds__(256) void k_gemm_nt(const short* __restrict__ A,
                                                 const short* __restrict__ B,
                                                 float* __restrict__ C,
                                                 int lda, int ldb, int ldc, int K) {
  __shared__ __align__(16) short As[128][64];
  __shared__ __align__(16) short Bs[128][64];
  const int t = threadIdx.x;
  const int w = t >> 6, l = t & 63;
  const int lr = l & 15, lh = l >> 4;
  const int m0 = blockIdx.y * 128, n0 = blockIdx.x * 128;
  const int wm = (w >> 1) * 64, wn = (w & 1) * 64;
  floatx4 acc[4][4] = {};
  for (int k0 = 0; k0 < K; k0 += 64) {
    __syncthreads();
#pragma unroll
    for (int i = 0; i < 4; ++i) {
      const int c = i * 256 + t;
      const int r = c >> 3, c8 = (c & 7) * 8;
      *(bf16x8*)&As[r][c8] = *(const bf16x8*)&A[(size_t)(m0 + r) * lda + k0 + c8];
      *(bf16x8*)&Bs[r][c8] = *(const bf16x8*)&B[(size_t)(n0 + r) * ldb + k0 + c8];
    }
    __syncthreads();
#pragma unroll
    for (int kk = 0; kk < 64; kk += 32) {
      bf16x8 af[4], bfr[4];
#pragma unroll
      for (int m = 0; m < 4; ++m) af[m] = *(const bf16x8*)&As[wm + m * 16 + lr][kk + lh * 8];
#pragma unroll
      for (int n = 0; n < 4; ++n) bfr[n] = *(const bf16x8*)&Bs[wn + n * 16 + lr][kk + lh * 8];
#pragma unroll
      for (int m = 0; m < 4; ++m)
#pragma unroll
        for (int n = 0; n < 4; ++n)
          acc[m][n] = __builtin_amdgcn_mfma_f32_16x16x32_bf16(af[m], bfr[n], acc[m][n], 0, 0, 0);
    }
  }
#pragma unroll
  for (int m = 0; m < 4; ++m)
#pragma unroll
    for (int n = 0; n < 4; ++n) {
      const int col = n0 + wn + n * 16 + lr;
#pragma unroll
      for (int j = 0; j < 4; ++j)
        C[(size_t)(m0 + wm + m * 16 + lh * 4 + j) * ldc + col] = acc[m][n][j];
    }
}

__global__ __launch_bounds__(256) void k_gemm_nt_f32a(const float* __restrict__ A,
                                                      const short* __restrict__ B,
                                                      float* __restrict__ C,
                                                      int lda, int ldb, int ldc, int K) {
  __shared__ __align__(16) short As[128][64];
  __shared__ __align__(16) short Bs[128][64];
  const int t = threadIdx.x;
  const int w = t >> 6, l = t & 63;
  const int lr = l & 15, lh = l >> 4;
  const int m0 = blockIdx.y * 128, n0 = blockIdx.x * 128;
  const int wm = (w >> 1) * 64, wn = (w & 1) * 64;
  floatx4 acc[4][4] = {};
  for (int k0 = 0; k0 < K; k0 += 64) {
    __syncthreads();
#pragma unroll
    for (int i = 0; i < 4; ++i) {
      const int c = i * 256 + t;
      const int r = c >> 3, c8 = (c & 7) * 8;
      const float4 a0 = *(const float4*)&A[(size_t)(m0 + r) * lda + k0 + c8];
      const float4 a1 = *(const float4*)&A[(size_t)(m0 + r) * lda + k0 + c8 + 4];
      bf16x8 va;
      va[0] = f2bf(a0.x); va[1] = f2bf(a0.y); va[2] = f2bf(a0.z); va[3] = f2bf(a0.w);
      va[4] = f2bf(a1.x); va[5] = f2bf(a1.y); va[6] = f2bf(a1.z); va[7] = f2bf(a1.w);
      *(bf16x8*)&As[r][c8] = va;
      *(bf16x8*)&Bs[r][c8] = *(const bf16x8*)&B[(size_t)(n0 + r) * ldb + k0 + c8];
    }
    __syncthreads();
#pragma unroll
    for (int kk = 0; kk < 64; kk += 32) {
      bf16x8 af[4], bfr[4];
#pragma unroll
      for (int m = 0; m < 4; ++m) af[m] = *(const bf16x8*)&As[wm + m * 16 + lr][kk + lh * 8];
#pragma unroll
      for (int n = 0; n < 4; ++n) bfr[n] = *(const bf16x8*)&Bs[wn + n * 16 + lr][kk + lh * 8];
#pragma unroll
      for (int m = 0; m < 4; ++m)
#pragma unroll
        for (int n = 0; n < 4; ++n)
          acc[m][n] = __builtin_amdgcn_mfma_f32_16x16x32_bf16(af[m], bfr[n], acc[m][n], 0, 0, 0);
    }
  }
#pragma unroll
  for (int m = 0; m < 4; ++m)
#pragma unroll
    for (int n = 0; n < 4; ++n) {
      const int col = n0 + wn + n * 16 + lr;
#pragma unroll
      for (int j = 0; j < 4; ++j)
        C[(size_t)(m0 + wm + m * 16 + lh * 4 + j) * ldc + col] = acc[m][n][j];
    }
}

__global__ __launch_bounds__(256) void k_gumbel_softmax(float* __restrict__ S,
                                                        const float* __restrict__ U) {
  const int t = threadIdx.x;
  const int w = t >> 6, l = t & 63;
  const size_t base = (size_t)blockIdx.x * V_DIM + t * 8;
  const float4 s0 = *(const float4*)&S[base];
  const float4 s1 = *(const float4*)&S[base + 4];
  const float4 u0 = *(const float4*)&U[base];
  const float4 u1 = *(const float4*)&U[base + 4];
  float x[8];
  x[0] = s0.x - 2.f * __logf(-__logf(u0.x + 1e-10f) + 1e-10f);
  x[1] = s0.y - 2.f * __logf(-__logf(u0.y + 1e-10f) + 1e-10f);
  x[2] = s0.z - 2.f * __logf(-__logf(u0.z + 1e-10f) + 1e-10f);
  x[3] = s0.w - 2.f * __logf(-__logf(u0.w + 1e-10f) + 1e-10f);
  x[4] = s1.x - 2.f * __logf(-__logf(u1.x + 1e-10f) + 1e-10f);
  x[5] = s1.y - 2.f * __logf(-__logf(u1.y + 1e-10f) + 1e-10f);
  x[6] = s1.z - 2.f * __logf(-__logf(u1.z + 1e-10f) + 1e-10f);
  x[7] = s1.w - 2.f * __logf(-__logf(u1.w + 1e-10f) + 1e-10f);
  float lm = x[0];
#pragma unroll
  for (int i = 1; i < 8; ++i) lm = fmaxf(lm, x[i]);
  lm = wave_max(lm);
  __shared__ float redA[4], redB[4];
  if (l == 0) redA[w] = lm;
  __syncthreads();
  const float m = fmaxf(fmaxf(redA[0], redA[1]), fmaxf(redA[2], redA[3]));
  float p[8];
  float ls = 0.f;
#pragma unroll
  for (int i = 0; i < 8; ++i) { p[i] = __expf(x[i] - m); ls += p[i]; }
  ls = wave_sum(ls);
  if (l == 0) redB[w] = ls;
  __syncthreads();
  const float inv = 1.0f / (redB[0] + redB[1] + redB[2] + redB[3]);
  float4 o0 = make_float4(p[0] * inv, p[1] * inv, p[2] * inv, p[3] * inv);
  float4 o1 = make_float4(p[4] * inv, p[5] * inv, p[6] * inv, p[7] * inv);
  *(float4*)&S[base] = o0;
  *(float4*)&S[base + 4] = o1;
}

extern "C" void kernel_launch(void* const* d_in, const int* in_sizes, int n_in,
                              void* d_out, int out_size, void* d_ws, size_t ws_size,
                              hipStream_t stream) {
  const float* z = (const float*)d_in[0];
  const float* W = (const float*)d_in[1];
  const float* U = (const float*)d_in[2];
  float* tokens = (float*)d_out;                    // [N, V] f32
  float* zq = tokens + (size_t)N_ROWS * V_DIM;      // [N, E] f32
  short* zn = (short*)zq;                           // bf16 zn in z_q region (fallback)
  unsigned char* zn8 =                              // fp8 zn (64 MB)
      (unsigned char*)zq + (size_t)N_ROWS * E_DIM * 2;

  short* embn = (short*)d_ws;                            // 4 MB (fallback)
  short* embnT = embn + (size_t)V_DIM * E_DIM;           // 4 MB
  unsigned char* embn8 = (unsigned char*)(embnT + (size_t)V_DIM * E_DIM);  // 2 MB

  const size_t NEED = (size_t)V_DIM * E_DIM * 2 * 2     // embn + embnT
                    + (size_t)V_DIM * E_DIM             // embn8
                    + (size_t)N_ROWS * 32 * 4           // partials (8 MB)
                    + (size_t)N_ROWS * 4                // invsum
                    + (size_t)N_ROWS * V_DIM * 2;       // P~ bf16 (256 MB)

  if (ws_size >= NEED) {
    float* partials = (float*)(embn8 + (size_t)V_DIM * E_DIM);
    float* invsum = partials + (size_t)N_ROWS * 32;
    short* Pb = (short*)(invsum + N_ROWS);
    // merged norms (fast: skip bf16 zn/embn stores)
    k_norm_all<1><<<V_DIM + N_ROWS / 4, 256, 0, stream>>>(
        z, W, zn, zn8, embn, embnT, embn8);
    // GEMM1 fp8 fused gumbel-exp: grid = (65536/256) * (2048/128) = 4096
    k_gemm_f8<<<4096, 512, 0, stream>>>(zn8, embn8, U, Pb, partials, 4096 / 8);
    k_rowsum_inv<<<N_ROWS / 256, 256, 0, stream>>>(partials, invsum);
    // GEMM2 bf16 scaled + streamed tokens: grid = 1024
    k_gemm8<V_DIM, 4><<<1024, 512, 0, stream>>>(
        Pb, embnT, invsum, zq, tokens, 1024 / 8);
  } else {
    k_norm_all<0><<<V_DIM + N_ROWS / 4, 256, 0, stream>>>(
        z, W, zn, zn8, embn, embnT, embn8);
    k_gemm_nt<<<dim3(V_DIM / 128, N_ROWS / 128), 256, 0, stream>>>(
        zn, embn, tokens, E_DIM, E_DIM, V_DIM, E_DIM);
    k_gumbel_softmax<<<N_ROWS, 256, 0, stream>>>(tokens, U);
    k_gemm_nt_f32a<<<dim3(E_DIM / 128, N_ROWS / 128), 256, 0, stream>>>(
        tokens, embnT, zq, V_DIM, V_DIM, E_DIM, V_DIM);
  }
}